// Round 6
// baseline (269.874 us; speedup 1.0000x reference)
//
#include <hip/hip_runtime.h>
#include <hip/hip_bf16.h>

#define BIGF 1e30f
#define TC 80   // channels
#define TN 512  // sequence length (N == M)
#define L2E 1.4426950408889634f   // log2(e)
#define LN2 0.6931471805599453f   // 1/log2(e)

typedef float f32x4 __attribute__((ext_vector_type(4)));
typedef __attribute__((address_space(1))) const unsigned int gu32;
typedef __attribute__((address_space(3))) unsigned int lu32;

// ---------------------------------------------------------------------------
// Kernel 1: pairwise squared distances, SKEWED ILP-2 layout, log2e-scaled.
//
// Logical: D'[j][i] = ||x_i - y_j||^2 (args swapped at launch; FP
// commutativity keeps values bitwise equal to D^T).
// Storage:  F[p][4v + w],  v = i>>2, w = i&3, p = (j + v) & 511 (0-indexed).
// Bijection into 512x512 floats per batch (for fixed v, p covers all
// residues). At sweep iteration s (127<=s<=511) all 128 pipelines read row
// p = s&511: one contiguous 2 KB block.
// ---------------------------------------------------------------------------
__global__ __launch_bounds__(256) void pairdist_kernel(
    const float* __restrict__ x, const float* __restrict__ y,
    float* __restrict__ F) {
  const int b  = blockIdx.z;
  const int n0 = blockIdx.x * 64;   // j tile (rows of D')
  const int m0 = blockIdx.y * 64;   // i tile (cols of D')

  __shared__ float xs[TC][64];
  __shared__ float ys[TC][64];
  __shared__ float xxs[64];
  __shared__ float yys[64];

  const float* xb = x + (size_t)b * TC * TN;
  const float* yb = y + (size_t)b * TC * TN;
  const int tid = threadIdx.x;

  for (int idx = tid; idx < TC * 64; idx += 256) {
    int c = idx >> 6, n = idx & 63;
    xs[c][n] = xb[c * TN + n0 + n];
    ys[c][n] = yb[c * TN + m0 + n];
  }
  __syncthreads();

  if (tid < 64) {
    float s = 0.f;
    for (int c = 0; c < TC; ++c) { float v = xs[c][tid]; s += v * v; }
    xxs[tid] = s;
  } else if (tid < 128) {
    int t2 = tid - 64;
    float s = 0.f;
    for (int c = 0; c < TC; ++c) { float v = ys[c][t2]; s += v * v; }
    yys[t2] = s;
  }
  __syncthreads();

  const int tm = tid & 15, tn = tid >> 4;
  float acc[4][4] = {};
  for (int c = 0; c < TC; ++c) {
    float4 xa = *(const float4*)&xs[c][tn * 4];
    float4 ya = *(const float4*)&ys[c][tm * 4];
    float xv[4] = {xa.x, xa.y, xa.z, xa.w};
    float yv[4] = {ya.x, ya.y, ya.z, ya.w};
#pragma unroll
    for (int a = 0; a < 4; ++a)
#pragma unroll
      for (int q = 0; q < 4; ++q) acc[a][q] += xv[a] * yv[q];
  }

  float* Fb = F + (size_t)b * TN * TN;
  const int vP = (m0 >> 2) + tm;          // pipeline id = i>>2 (float4 = one pipeline)
#pragma unroll
  for (int a = 0; a < 4; ++a) {
    int jj = n0 + tn * 4 + a;             // row of D' (0-indexed j)
    float xxv = xxs[tn * 4 + a];
    float4 o;
    o.x = (xxv + yys[tm * 4 + 0] - 2.f * acc[a][0]) * L2E;
    o.y = (xxv + yys[tm * 4 + 1] - 2.f * acc[a][1]) * L2E;
    o.z = (xxv + yys[tm * 4 + 2] - 2.f * acc[a][2]) * L2E;
    o.w = (xxv + yys[tm * 4 + 3] - 2.f * acc[a][3]) * L2E;
    int p = (jj + vP) & (TN - 1);
    *(float4*)&Fb[(size_t)p * TN + vP * 4] = o;
  }
}

// ---------------------------------------------------------------------------
// Kernel 2: soft-DTW, ILP-2 slab sweep (128 virtual pipelines), LDS ring
// (depth 8) with BATCHED atomic ds_reads (4 slots per lgkmcnt(0) block).
//
// Pipeline v owns DP rows 4v+1..4v+4; lane t runs v=2t (A) and v=2t+1 (B).
// At iteration s, pipeline v is at column j = s-v+1. Both 4-cell chains
// depend only on previous-iteration values (B's up = A's bottom from s-1,
// in-register; A's up = lane t-1's B bottom via DPP wave_shr:1, old=BIG),
// so the per-iteration critical path is 4 cells, not 8. 639 iterations.
//
// vmcnt invariant: preamble stages 8 slots (16 DMA). Each batch: wait
// vmcnt(8) [the 4 slots about to be read have landed], atomic 8x
// ds_read_b128 + lgkmcnt(0) (outputs complete at asm exit - sound), refill
// the 4 slots (back to 16 outstanding). Tail batches skip refill; the
// second tail batch waits vmcnt(0).
//
// BIG=1e30 self-sustains bitwise in log2 domain (log2(3), dv << ulp(1e30)).
// Junk (clamped) columns only feed pre/post-range cells. Reassociated
// cur = (dv+m3) - log2(ss): dv+m3 runs parallel to the exps.
// ---------------------------------------------------------------------------
__global__ __launch_bounds__(64) __attribute__((amdgpu_waves_per_eu(1)))
void sdtw_kernel(const float* __restrict__ Ft, float* __restrict__ out) {
  const int b = blockIdx.x;
  const int t = threadIdx.x;
  const float* Fb = Ft + (size_t)b * TN * TN;

  __shared__ float ring[8][512];      // 8 slots x 2 KB

  float pA[4], pB[4];                 // R[i][j-1] for the two 4-row groups
#pragma unroll
  for (int r = 0; r < 4; ++r) { pA[r] = BIGF; pB[r] = BIGF; }
  float upA_c = BIGF;                       // R[8t][j]     (A's up row)
  float upA_p = (t == 0) ? 0.f : BIGF;      // R[8t][j-1];  R[0][0]=0
  float upB_c = BIGF;                       // R[8t+4][j]   (B's up row)
  float upB_p = BIGF;                       // R[8t+4][j-1]

  // Stage slot <- iteration u's data: A = F[pa][8t..8t+3], B = F[pb][8t+4..].
  auto stageAB = [&](int slot, int u) {
    int va = u - 2 * t;
    va = va < 0 ? 0 : (va > TN - 1 ? TN - 1 : va);
    int pa = (va + 2 * t) & (TN - 1);
    int vb = u - 2 * t - 1;
    vb = vb < 0 ? 0 : (vb > TN - 1 ? TN - 1 : vb);
    int pb = (vb + 2 * t + 1) & (TN - 1);
    const float* gA = Fb + (size_t)pa * TN + t * 8;
    const float* gB = Fb + (size_t)pb * TN + t * 8 + 4;
    __builtin_amdgcn_global_load_lds((gu32*)gA, (lu32*)&ring[slot][0],   16, 0, 0);
    __builtin_amdgcn_global_load_lds((gu32*)gB, (lu32*)&ring[slot][256], 16, 0, 0);
  };

  const unsigned lbase =
      (unsigned)(size_t)(__attribute__((address_space(3))) float*)&ring[0][0];

  // Atomic batched read of 4 slots (k0..k0+3): outputs complete at asm exit.
  auto batch_read = [&](int k0, f32x4& a0, f32x4& b0, f32x4& a1, f32x4& b1,
                        f32x4& a2, f32x4& b2, f32x4& a3, f32x4& b3) {
    unsigned ad = lbase + (unsigned)(k0 * 2048) + (unsigned)(t * 16);
    asm volatile("ds_read_b128 %0, %8\n\t"
                 "ds_read_b128 %1, %8 offset:1024\n\t"
                 "ds_read_b128 %2, %8 offset:2048\n\t"
                 "ds_read_b128 %3, %8 offset:3072\n\t"
                 "ds_read_b128 %4, %8 offset:4096\n\t"
                 "ds_read_b128 %5, %8 offset:5120\n\t"
                 "ds_read_b128 %6, %8 offset:6144\n\t"
                 "ds_read_b128 %7, %8 offset:7168\n\t"
                 "s_waitcnt lgkmcnt(0)"
                 : "=&v"(a0), "=&v"(b0), "=&v"(a1), "=&v"(b1),
                   "=&v"(a2), "=&v"(b2), "=&v"(a3), "=&v"(b3)
                 : "v"(ad)
                 : "memory");
  };

  auto body = [&](f32x4 dA, f32x4 dB) {
    // A chain (4 dependent cells)
    float r0 = upA_p, r1 = upA_c;
#pragma unroll
    for (int r = 0; r < 4; ++r) {
      float r2 = pA[r];
      float m3 = fminf(fminf(r0, r1), r2);
      float dm = dA[r] + m3;
      float ss = __builtin_amdgcn_exp2f(m3 - r0) +
                 __builtin_amdgcn_exp2f(m3 - r1) +
                 __builtin_amdgcn_exp2f(m3 - r2);
      float cur = dm - __builtin_amdgcn_logf(ss);
      r0 = r2; pA[r] = cur; r1 = cur;
    }
    // B chain (independent of A within this iteration)
    float q0 = upB_p, q1 = upB_c;
#pragma unroll
    for (int r = 0; r < 4; ++r) {
      float q2 = pB[r];
      float m3 = fminf(fminf(q0, q1), q2);
      float dm = dB[r] + m3;
      float ss = __builtin_amdgcn_exp2f(m3 - q0) +
                 __builtin_amdgcn_exp2f(m3 - q1) +
                 __builtin_amdgcn_exp2f(m3 - q2);
      float cur = dm - __builtin_amdgcn_logf(ss);
      q0 = q2; pB[r] = cur; q1 = cur;
    }
    // Cross-pipeline passes (all from THIS iteration's bottoms, consumed next).
    upB_p = upB_c; upB_c = pA[3];       // B's up row = A's bottom (lane-local)
    upA_p = upA_c;
    int sh = __builtin_amdgcn_update_dpp(
        __float_as_int(BIGF), __float_as_int(pB[3]), 0x138, 0xf, 0xf, false);
    upA_c = __int_as_float(sh);         // A's up row = lane t-1's B bottom
  };

  // Preamble: stage slots 0..7 for iterations 0..7 -> 16 outstanding DMA.
  stageAB(0, 0); stageAB(1, 1); stageAB(2, 2); stageAB(3, 3);
  stageAB(4, 4); stageAB(5, 5); stageAB(6, 6); stageAB(7, 7);

  f32x4 a0, b0, a1, b1, a2, b2, a3, b3;

  // Main: 79 x 8 bodies (s = 0..631).
  int s = 0;
  for (int blk = 0; blk < 79; ++blk, s += 8) {
    asm volatile("s_waitcnt vmcnt(8)" ::: "memory");
    batch_read(0, a0, b0, a1, b1, a2, b2, a3, b3);
    stageAB(0, s + 8);  stageAB(1, s + 9);
    stageAB(2, s + 10); stageAB(3, s + 11);
    body(a0, b0); body(a1, b1); body(a2, b2); body(a3, b3);

    asm volatile("s_waitcnt vmcnt(8)" ::: "memory");
    batch_read(4, a0, b0, a1, b1, a2, b2, a3, b3);
    stageAB(4, s + 12); stageAB(5, s + 13);
    stageAB(6, s + 14); stageAB(7, s + 15);
    body(a0, b0); body(a1, b1); body(a2, b2); body(a3, b3);
  }

  // Tail: bodies 632..638 (no refills).
  asm volatile("s_waitcnt vmcnt(8)" ::: "memory");
  batch_read(0, a0, b0, a1, b1, a2, b2, a3, b3);
  body(a0, b0); body(a1, b1); body(a2, b2); body(a3, b3);   // 632..635

  asm volatile("s_waitcnt vmcnt(0)" ::: "memory");
  batch_read(4, a0, b0, a1, b1, a2, b2, a3, b3);
  body(a0, b0); body(a1, b1); body(a2, b2);                 // 636..638

  // R[512][512] = pipeline v=127 (lane 63, B), bottom row, at s=638.
  if (t == 63) out[b] = pB[3] * LN2;
}

extern "C" void kernel_launch(void* const* d_in, const int* in_sizes, int n_in,
                              void* d_out, int out_size, void* d_ws, size_t ws_size,
                              hipStream_t stream) {
  const float* x = (const float*)d_in[0];
  const float* y = (const float*)d_in[1];
  float* out = (float*)d_out;
  float* F = (float*)d_ws;  // 32*512*512*4 = 33.5 MB, skewed ILP-2 layout

  dim3 g1(TN / 64, TN / 64, 32);
  // Swapped args -> values are bitwise D^T, stored skewed + log2e-scaled.
  pairdist_kernel<<<g1, 256, 0, stream>>>(y, x, F);
  sdtw_kernel<<<32, 64, 0, stream>>>(F, out);
}

// Round 7
// 263.095 us; speedup vs baseline: 1.0258x; 1.0258x over previous
//
#include <hip/hip_runtime.h>
#include <hip/hip_bf16.h>

#define BIGF 1e30f
#define TC 80   // channels
#define TN 512  // sequence length (N == M)
#define L2E 1.4426950408889634f   // log2(e)
#define LN2 0.6931471805599453f   // 1/log2(e)

typedef float f32x4 __attribute__((ext_vector_type(4)));
typedef __attribute__((address_space(1))) const unsigned int gu32;
typedef __attribute__((address_space(3))) unsigned int lu32;

// ---------------------------------------------------------------------------
// Kernel 1: pairwise squared distances, SKEWED ILP-2 layout, log2e-scaled.
// (unchanged from round 6 — verified absmax 0.0)
// ---------------------------------------------------------------------------
__global__ __launch_bounds__(256) void pairdist_kernel(
    const float* __restrict__ x, const float* __restrict__ y,
    float* __restrict__ F) {
  const int b  = blockIdx.z;
  const int n0 = blockIdx.x * 64;   // j tile (rows of D')
  const int m0 = blockIdx.y * 64;   // i tile (cols of D')

  __shared__ float xs[TC][64];
  __shared__ float ys[TC][64];
  __shared__ float xxs[64];
  __shared__ float yys[64];

  const float* xb = x + (size_t)b * TC * TN;
  const float* yb = y + (size_t)b * TC * TN;
  const int tid = threadIdx.x;

  for (int idx = tid; idx < TC * 64; idx += 256) {
    int c = idx >> 6, n = idx & 63;
    xs[c][n] = xb[c * TN + n0 + n];
    ys[c][n] = yb[c * TN + m0 + n];
  }
  __syncthreads();

  if (tid < 64) {
    float s = 0.f;
    for (int c = 0; c < TC; ++c) { float v = xs[c][tid]; s += v * v; }
    xxs[tid] = s;
  } else if (tid < 128) {
    int t2 = tid - 64;
    float s = 0.f;
    for (int c = 0; c < TC; ++c) { float v = ys[c][t2]; s += v * v; }
    yys[t2] = s;
  }
  __syncthreads();

  const int tm = tid & 15, tn = tid >> 4;
  float acc[4][4] = {};
  for (int c = 0; c < TC; ++c) {
    float4 xa = *(const float4*)&xs[c][tn * 4];
    float4 ya = *(const float4*)&ys[c][tm * 4];
    float xv[4] = {xa.x, xa.y, xa.z, xa.w};
    float yv[4] = {ya.x, ya.y, ya.z, ya.w};
#pragma unroll
    for (int a = 0; a < 4; ++a)
#pragma unroll
      for (int q = 0; q < 4; ++q) acc[a][q] += xv[a] * yv[q];
  }

  float* Fb = F + (size_t)b * TN * TN;
  const int vP = (m0 >> 2) + tm;          // pipeline id = i>>2
#pragma unroll
  for (int a = 0; a < 4; ++a) {
    int jj = n0 + tn * 4 + a;             // row of D'
    float xxv = xxs[tn * 4 + a];
    float4 o;
    o.x = (xxv + yys[tm * 4 + 0] - 2.f * acc[a][0]) * L2E;
    o.y = (xxv + yys[tm * 4 + 1] - 2.f * acc[a][1]) * L2E;
    o.z = (xxv + yys[tm * 4 + 2] - 2.f * acc[a][2]) * L2E;
    o.w = (xxv + yys[tm * 4 + 3] - 2.f * acc[a][3]) * L2E;
    int p = (jj + vP) & (TN - 1);
    *(float4*)&Fb[(size_t)p * TN + vP * 4] = o;
  }
}

// ---------------------------------------------------------------------------
// Kernel 2: soft-DTW ILP-2 slab sweep. Round-7 changes (structure otherwise
// = verified round 6):
//  (1) A/B chains FUSED per cell-step so the scheduler interleaves the two
//      independent dependence chains (round 6 evidence: they serialized).
//  (2) 3 trans/cell instead of 4: min3/med3/max3 (exact single-instr sort)
//      -> the min's exp2 term is exactly 1; ss = (1+e_med)+e_max. Trans-pipe
//      load/iter 256 -> 192 cy. BIG self-sustain unchanged (ss=3 path).
//  (3) One atomic 16x ds_read_b128 + lgkmcnt(0) per 8 BODIES (whole ring),
//      then refill all 8 slots, then 8 bodies. vmcnt(0) at block top waits
//      for DMAs staged one block (~2400 cy) earlier -> near-free.
// 639 iterations = 79 blocks x 8 + 7 tail.
// ---------------------------------------------------------------------------
__global__ __launch_bounds__(64) __attribute__((amdgpu_waves_per_eu(1)))
void sdtw_kernel(const float* __restrict__ Ft, float* __restrict__ out) {
  const int b = blockIdx.x;
  const int t = threadIdx.x;
  const float* Fb = Ft + (size_t)b * TN * TN;

  __shared__ float ring[8][512];      // 8 slots x 2 KB

  float pA[4], pB[4];
#pragma unroll
  for (int r = 0; r < 4; ++r) { pA[r] = BIGF; pB[r] = BIGF; }
  float upA_c = BIGF;                       // R[8t][j]
  float upA_p = (t == 0) ? 0.f : BIGF;      // R[8t][j-1]; R[0][0]=0
  float upB_c = BIGF;                       // R[8t+4][j]
  float upB_p = BIGF;                       // R[8t+4][j-1]

  auto stageAB = [&](int slot, int u) {
    int va = u - 2 * t;
    va = va < 0 ? 0 : (va > TN - 1 ? TN - 1 : va);
    int pa = (va + 2 * t) & (TN - 1);
    int vb = u - 2 * t - 1;
    vb = vb < 0 ? 0 : (vb > TN - 1 ? TN - 1 : vb);
    int pb = (vb + 2 * t + 1) & (TN - 1);
    const float* gA = Fb + (size_t)pa * TN + t * 8;
    const float* gB = Fb + (size_t)pb * TN + t * 8 + 4;
    __builtin_amdgcn_global_load_lds((gu32*)gA, (lu32*)&ring[slot][0],   16, 0, 0);
    __builtin_amdgcn_global_load_lds((gu32*)gB, (lu32*)&ring[slot][256], 16, 0, 0);
  };

  const unsigned lbase =
      (unsigned)(size_t)(__attribute__((address_space(3))) float*)&ring[0][0];

  // Fused A/B cell-step body: both 4-cell chains advance together so their
  // trans latencies overlap. 3 trans per cell via exact min3/med3/max3.
  auto body = [&](f32x4 dA, f32x4 dB) {
    float r0 = upA_p, r1 = upA_c;
    float q0 = upB_p, q1 = upB_c;
#pragma unroll
    for (int r = 0; r < 4; ++r) {
      float r2 = pA[r], q2 = pB[r];
      float am, amd, amx, bm, bmd, bmx;
      asm("v_min3_f32 %0, %3, %4, %5\n\t"
          "v_med3_f32 %1, %3, %4, %5\n\t"
          "v_max3_f32 %2, %3, %4, %5"
          : "=&v"(am), "=&v"(amd), "=&v"(amx)
          : "v"(r0), "v"(r1), "v"(r2));
      asm("v_min3_f32 %0, %3, %4, %5\n\t"
          "v_med3_f32 %1, %3, %4, %5\n\t"
          "v_max3_f32 %2, %3, %4, %5"
          : "=&v"(bm), "=&v"(bmd), "=&v"(bmx)
          : "v"(q0), "v"(q1), "v"(q2));
      float ae1 = __builtin_amdgcn_exp2f(am - amd);
      float be1 = __builtin_amdgcn_exp2f(bm - bmd);
      float ae2 = __builtin_amdgcn_exp2f(am - amx);
      float be2 = __builtin_amdgcn_exp2f(bm - bmx);
      float adm = dA[r] + am;
      float bdm = dB[r] + bm;
      float ass = (1.0f + ae1) + ae2;
      float bss = (1.0f + be1) + be2;
      float acur = adm - __builtin_amdgcn_logf(ass);
      float bcur = bdm - __builtin_amdgcn_logf(bss);
      r0 = r2; pA[r] = acur; r1 = acur;
      q0 = q2; pB[r] = bcur; q1 = bcur;
    }
    upB_p = upB_c; upB_c = pA[3];       // B's up = A's bottom (lane-local)
    upA_p = upA_c;
    int sh = __builtin_amdgcn_update_dpp(
        __float_as_int(BIGF), __float_as_int(pB[3]), 0x138, 0xf, 0xf, false);
    upA_c = __int_as_float(sh);         // A's up = lane t-1's B bottom
  };

  // Preamble: stage slots 0..7 (iters 0..7) -> 16 outstanding DMA.
  stageAB(0, 0); stageAB(1, 1); stageAB(2, 2); stageAB(3, 3);
  stageAB(4, 4); stageAB(5, 5); stageAB(6, 6); stageAB(7, 7);

  f32x4 a0, b0, a1, b1, a2, b2, a3, b3, a4, b4, a5, b5, a6, b6, a7, b7;

  // Main: 79 blocks x 8 bodies (iters 0..631).
  int s = 0;
  for (int blk = 0; blk < 79; ++blk, s += 8) {
    // All 16 DMAs staged last block have landed after this wait (issued
    // ~8 bodies ago -> near-zero stall).
    asm volatile("s_waitcnt vmcnt(0)" ::: "memory");
    // Atomic whole-ring read: outputs complete at asm exit.
    unsigned ad = lbase + (unsigned)(t * 16);
    asm volatile(
        "ds_read_b128 %0, %16\n\t"
        "ds_read_b128 %1, %16 offset:1024\n\t"
        "ds_read_b128 %2, %16 offset:2048\n\t"
        "ds_read_b128 %3, %16 offset:3072\n\t"
        "ds_read_b128 %4, %16 offset:4096\n\t"
        "ds_read_b128 %5, %16 offset:5120\n\t"
        "ds_read_b128 %6, %16 offset:6144\n\t"
        "ds_read_b128 %7, %16 offset:7168\n\t"
        "ds_read_b128 %8, %16 offset:8192\n\t"
        "ds_read_b128 %9, %16 offset:9216\n\t"
        "ds_read_b128 %10, %16 offset:10240\n\t"
        "ds_read_b128 %11, %16 offset:11264\n\t"
        "ds_read_b128 %12, %16 offset:12288\n\t"
        "ds_read_b128 %13, %16 offset:13312\n\t"
        "ds_read_b128 %14, %16 offset:14336\n\t"
        "ds_read_b128 %15, %16 offset:15360\n\t"
        "s_waitcnt lgkmcnt(0)"
        : "=&v"(a0), "=&v"(b0), "=&v"(a1), "=&v"(b1),
          "=&v"(a2), "=&v"(b2), "=&v"(a3), "=&v"(b3),
          "=&v"(a4), "=&v"(b4), "=&v"(a5), "=&v"(b5),
          "=&v"(a6), "=&v"(b6), "=&v"(a7), "=&v"(b7)
        : "v"(ad)
        : "memory");
    // Refill all 8 slots for the NEXT block (reads above already complete).
    stageAB(0, s + 8);  stageAB(1, s + 9);
    stageAB(2, s + 10); stageAB(3, s + 11);
    stageAB(4, s + 12); stageAB(5, s + 13);
    stageAB(6, s + 14); stageAB(7, s + 15);

    body(a0, b0); body(a1, b1); body(a2, b2); body(a3, b3);
    body(a4, b4); body(a5, b5); body(a6, b6); body(a7, b7);
  }

  // Tail: iters 632..638 (7 bodies, slots 0..6; no refills).
  asm volatile("s_waitcnt vmcnt(0)" ::: "memory");
  {
    unsigned ad = lbase + (unsigned)(t * 16);
    asm volatile(
        "ds_read_b128 %0, %14\n\t"
        "ds_read_b128 %1, %14 offset:1024\n\t"
        "ds_read_b128 %2, %14 offset:2048\n\t"
        "ds_read_b128 %3, %14 offset:3072\n\t"
        "ds_read_b128 %4, %14 offset:4096\n\t"
        "ds_read_b128 %5, %14 offset:5120\n\t"
        "ds_read_b128 %6, %14 offset:6144\n\t"
        "ds_read_b128 %7, %14 offset:7168\n\t"
        "ds_read_b128 %8, %14 offset:8192\n\t"
        "ds_read_b128 %9, %14 offset:9216\n\t"
        "ds_read_b128 %10, %14 offset:10240\n\t"
        "ds_read_b128 %11, %14 offset:11264\n\t"
        "ds_read_b128 %12, %14 offset:12288\n\t"
        "ds_read_b128 %13, %14 offset:13312\n\t"
        "s_waitcnt lgkmcnt(0)"
        : "=&v"(a0), "=&v"(b0), "=&v"(a1), "=&v"(b1),
          "=&v"(a2), "=&v"(b2), "=&v"(a3), "=&v"(b3),
          "=&v"(a4), "=&v"(b4), "=&v"(a5), "=&v"(b5),
          "=&v"(a6), "=&v"(b6)
        : "v"(ad)
        : "memory");
  }
  body(a0, b0); body(a1, b1); body(a2, b2); body(a3, b3);
  body(a4, b4); body(a5, b5); body(a6, b6);               // 632..638

  // R[512][512] = pipeline v=127 (lane 63, B), bottom row, at s=638.
  if (t == 63) out[b] = pB[3] * LN2;
}

extern "C" void kernel_launch(void* const* d_in, const int* in_sizes, int n_in,
                              void* d_out, int out_size, void* d_ws, size_t ws_size,
                              hipStream_t stream) {
  const float* x = (const float*)d_in[0];
  const float* y = (const float*)d_in[1];
  float* out = (float*)d_out;
  float* F = (float*)d_ws;  // 32*512*512*4 = 33.5 MB, skewed ILP-2 layout

  dim3 g1(TN / 64, TN / 64, 32);
  // Swapped args -> values are bitwise D^T, stored skewed + log2e-scaled.
  pairdist_kernel<<<g1, 256, 0, stream>>>(y, x, F);
  sdtw_kernel<<<32, 64, 0, stream>>>(F, out);
}